// Round 5
// baseline (120.950 us; speedup 1.0000x reference)
//
#include <hip/hip_runtime.h>
#include <hip/hip_bf16.h>

// SimilarityLayer: out[e,q,w,n,m] = <p[e,w,:,n], q[e,q,:,m]> / (|p||q| + 1e-8)
// E=8 W=5 C=640 N=49 Q=75.
// R5: one block per (e,q): [256x640]x[640x64(49 used)] -> contiguous 48KB out slice
//     (fixes R4's 2.7x write inflation). Kc=32, A-image pre-swizzled bf16 in ws,
//     3-buffer A via global_load_lds issued 2 chunks ahead, 2-deep B register
//     prefetch, raw s_barrier with counted vmcnt(12) (T3+T4: loads stay in
//     flight across barriers). e = bid&7 pins each e's A-image to one XCD L2.

#define E_CNT 8
#define W_CNT 5
#define C_CNT 640
#define N_CNT 49
#define Q_CNT 75
#define MROWS 245                   // W*N
#define NC32 20                     // K chunks of 32
#define ACH 16384                   // bytes per (e, chunk32) A-image chunk (256 rows x 64 B)
#define ASW_SIZE (E_CNT * NC32 * ACH)
#define PN_OFF ASW_SIZE
#define PN_PART_BYTES (E_CNT * 10 * MROWS * 4)
#define WS_NEEDED ((size_t)(PN_OFF + PN_PART_BYTES))

// GEMM LDS: A 3x16384 @0 ; B 2x4096 @49152 ; qn 64f @57344 ; pnl 245f @57600
#define LDSB_OFF 49152
#define QN_OFF 57344
#define PNL_OFF 57600
#define SM_BYTES 58624

typedef __attribute__((ext_vector_type(8))) short bf16x8;
typedef __attribute__((ext_vector_type(4))) float f32x4;

static __device__ __forceinline__ short f2bf(float f) {
    __hip_bfloat16 h = __float2bfloat16(f);
    return *reinterpret_cast<short*>(&h);
}

// Paired-row XOR swizzle for 32-K chunks: row in [0,256), lk in [0,4) (8 k's each).
// 16 consecutive rows at fixed lk -> each bank-quad hit exactly 2x (free).
static __device__ __forceinline__ int ainner(int row, int lk) {
    return ((row >> 1) << 7) + (((((row & 1) << 2) | lk) ^ ((row >> 1) & 7)) << 4);
}

static __device__ __forceinline__ void gload16(const void* g, void* l) {
    __builtin_amdgcn_global_load_lds(
        (const __attribute__((address_space(1))) void*)g,
        (__attribute__((address_space(3))) void*)l, 16, 0, 0);
}

// ---------------- prep: proto -> swizzled bf16 A image + partial norms -------
__global__ __launch_bounds__(256, 4)
void prep_kernel(const float* __restrict__ proto,
                 unsigned char* __restrict__ asw,
                 float* __restrict__ pn_part)
{
    __shared__ float pns[MROWS];
    const int b = blockIdx.x;           // 80 = e*10 + c64
    const int e = b / 10, c64 = b % 10;
    const float* pbase = proto + (size_t)e * (W_CNT * C_CNT * N_CNT);
    unsigned char* ebase = asw + (size_t)e * NC32 * ACH;
    const int t = threadIdx.x;
    if (t < MROWS) pns[t] = 0.f;
    __syncthreads();

    #pragma unroll
    for (int i = 0; i < 8; ++i) {
        const int s = t + i * 256;      // slot = kb*245 + nw, kb in [0,8)
        if (s < 8 * MROWS) {
            const int kb = s / MROWS;
            const int nw = s - kb * MROWS;
            const int w = nw / N_CNT, n = nw - w * N_CNT;
            const float* g = pbase + ((size_t)(w * C_CNT + c64 * 64 + kb * 8)) * N_CNT + n;
            float vv[8];
            #pragma unroll
            for (int j = 0; j < 8; ++j) vv[j] = g[(size_t)j * N_CNT];
            float ss = 0.f;
            bf16x8 pk;
            #pragma unroll
            for (int j = 0; j < 8; ++j) { const float f = vv[j]; ss += f * f; pk[j] = f2bf(f); }
            const int c32 = c64 * 2 + (kb >> 2);
            *reinterpret_cast<bf16x8*>(ebase + (size_t)c32 * ACH + ainner(nw, kb & 3)) = pk;
            atomicAdd(&pns[nw], ss);
        } else {
            const int x = s - 8 * MROWS;        // zero-pad rows 245..255, all granules
            const int nw = MROWS + (x >> 3), kb = x & 7;
            const int c32 = c64 * 2 + (kb >> 2);
            *reinterpret_cast<bf16x8*>(ebase + (size_t)c32 * ACH + ainner(nw, kb & 3)) =
                (bf16x8){0, 0, 0, 0, 0, 0, 0, 0};
        }
    }
    __syncthreads();
    if (t < MROWS) pn_part[(size_t)(e * 10 + c64) * MROWS + t] = pns[t];
}

// ---------------- GEMM: one block per (e,q): [256 x 640] x [640 x 64] --------
__global__ __launch_bounds__(256, 2)
void gemm_kernel(const float* __restrict__ query,
                 const unsigned char* __restrict__ asw,
                 const float* __restrict__ pn_part,
                 float* __restrict__ out)
{
    extern __shared__ unsigned char sm[];
    const int b = blockIdx.x;           // 600
    const int e = b & 7;                // same e -> same XCD -> A image L2-resident
    const int q = b >> 3;
    const int t = threadIdx.x;
    const int wv = t >> 6, ln = t & 63;
    const int lrow = ln & 15, lk = ln >> 4;

    const unsigned char* aimg = asw + (size_t)e * NC32 * ACH;
    const float* qsl = query + (size_t)(e * Q_CNT + q) * (C_CNT * N_CNT);

    // B staging: thread owns col r (64, 49 valid), k-granule kb (8 k's)
    const int r = t & 63;
    const int kb = t >> 6;              // 0..3
    const bool validr = r < N_CNT;
    const float* qcol = qsl + r;
    const int bwoff = ainner(r, kb);

    float* qn = (float*)(sm + QN_OFF);
    float* pnl = (float*)(sm + PNL_OFF);
    if (t < 64) qn[t] = 0.f;

    float vb[2][8];
    float ss_tot = 0.f;

    f32x4 acc[4][4];
    #pragma unroll
    for (int i = 0; i < 4; ++i)
        #pragma unroll
        for (int j = 0; j < 4; ++j) acc[i][j] = (f32x4){0.f, 0.f, 0.f, 0.f};

#define A_ISSUE(c, buf) do {                                                    \
    const unsigned char* ag_ = aimg + (size_t)(c) * ACH;                        \
    _Pragma("unroll")                                                           \
    for (int i_ = 0; i_ < 4; ++i_)                                              \
        gload16(ag_ + (t + i_ * 256) * 16, sm + (buf) * 16384 + (t + i_ * 256) * 16); \
} while (0)

#define B_LOAD(c, slot) do {                                                    \
    _Pragma("unroll")                                                           \
    for (int j_ = 0; j_ < 8; ++j_)                                              \
        vb[slot][j_] = validr ? qcol[(size_t)((c) * 32 + kb * 8 + j_) * N_CNT] : 0.f; \
} while (0)

#define B_WRITE(slot, buf) do {                                                 \
    bf16x8 pk_; float s8_ = 0.f;                                                \
    _Pragma("unroll")                                                           \
    for (int j_ = 0; j_ < 8; ++j_) {                                            \
        const float f_ = vb[slot][j_]; s8_ += f_ * f_; pk_[j_] = f2bf(f_);      \
    }                                                                           \
    ss_tot += s8_;                                                              \
    *reinterpret_cast<bf16x8*>(sm + LDSB_OFF + (buf) * 4096 + bwoff) = pk_;     \
} while (0)

// Counted-vmcnt barrier: A(c+2)[4 gload16] + B(c+2)[8 loads] = 12 stay in flight;
// vmcnt is issue-ordered, so <=12 outstanding guarantees A(c+1)/B(c+1) landed.
#define PIPE_BARRIER() asm volatile(                                            \
    "s_waitcnt vmcnt(12)\n\ts_waitcnt lgkmcnt(0)\n\ts_barrier" ::: "memory")

    // prologue: A chunks 0,1 staged; B chunks 0,1 loaded; B0 written
    A_ISSUE(0, 0);
    A_ISSUE(1, 1);
    B_LOAD(0, 0);
    B_LOAD(1, 1);
    B_WRITE(0, 0);
    PIPE_BARRIER();

    for (int c = 0; c < NC32; ++c) {
        const int c3 = c % 3, cb = c & 1;
        if (c < NC32 - 2) {
            A_ISSUE(c + 2, (c + 2) % 3);
            B_LOAD(c + 2, cb);          // (c+2)&1 == cb
        }

        // MFMA on A buf c3, B buf cb (wave tile 64 rows x 64 cols)
        {
            const unsigned char* Ab = sm + c3 * 16384;
            const unsigned char* Bb = sm + LDSB_OFF + cb * 4096;
            bf16x8 af[4], bfr[4];
            #pragma unroll
            for (int fi = 0; fi < 4; ++fi) {
                const int row = wv * 64 + fi * 16 + lrow;
                af[fi] = *reinterpret_cast<const bf16x8*>(Ab + ainner(row, lk));
            }
            #pragma unroll
            for (int fj = 0; fj < 4; ++fj) {
                const int col = fj * 16 + lrow;
                bfr[fj] = *reinterpret_cast<const bf16x8*>(Bb + ainner(col, lk));
            }
            #pragma unroll
            for (int fi = 0; fi < 4; ++fi)
                #pragma unroll
                for (int fj = 0; fj < 4; ++fj)
                    acc[fi][fj] = __builtin_amdgcn_mfma_f32_16x16x32_bf16(
                        af[fi], bfr[fj], acc[fi][fj], 0, 0, 0);
        }

        if (c < NC32 - 1) {
            B_WRITE((c + 1) & 1, (c + 1) & 1);
            PIPE_BARRIER();
        }
    }

    // ---- norms ----
    atomicAdd(&qn[r], ss_tot);          // 4 threads per col; padded cols add 0
    if (t < MROWS) {
        float s = 0.f;
        #pragma unroll
        for (int cc = 0; cc < 10; ++cc) s += pn_part[(size_t)(e * 10 + cc) * MROWS + t];
        pnl[t] = sqrtf(s);
    }
    __syncthreads();

    // ---- epilogue: contiguous 48KB slice out[(e*75+q)*12005 + nw*49 + m] ----
    float nq4[4];
    #pragma unroll
    for (int fj = 0; fj < 4; ++fj) {
        const int col = fj * 16 + lrow;
        nq4[fj] = (col < N_CNT) ? sqrtf(qn[col]) : 1.f;
    }
    float* osl = out + (size_t)(e * Q_CNT + q) * (W_CNT * N_CNT * N_CNT);
    #pragma unroll
    for (int fi = 0; fi < 4; ++fi) {
        #pragma unroll
        for (int rr = 0; rr < 4; ++rr) {
            const int nw = wv * 64 + fi * 16 + lk * 4 + rr;   // D row = (lane>>4)*4+reg
            if (nw < MROWS) {
                const float np_ = pnl[nw];
                #pragma unroll
                for (int fj = 0; fj < 4; ++fj) {
                    const int m = fj * 16 + lrow;             // D col = lane&15
                    if (m < N_CNT) {
                        const float den = np_ * nq4[fj] + 1e-8f;
                        osl[nw * N_CNT + m] = acc[fi][fj][rr] * __builtin_amdgcn_rcpf(den);
                    }
                }
            }
        }
    }
#undef A_ISSUE
#undef B_LOAD
#undef B_WRITE
#undef PIPE_BARRIER
}

// ---------------- fallback (R2 kernel) if ws too small -----------------------
struct SMemFB {
    unsigned char A[256 * 128];
    unsigned char B[64 * 128];
    float ns[320];
};

__global__ __launch_bounds__(512, 4)
void sim_fallback_kernel(const float* __restrict__ proto,
                         const float* __restrict__ query,
                         float* __restrict__ out)
{
    __shared__ SMemFB smf;
    const int t = threadIdx.x;
    const int e = blockIdx.x / Q_CNT;
    const int q = blockIdx.x - e * Q_CNT;
    const float* pbase = proto + (size_t)e * (W_CNT * C_CNT * N_CNT);
    const float* qbase = query + ((size_t)e * Q_CNT + q) * (C_CNT * N_CNT);
    unsigned char* lds = (unsigned char*)&smf;
    if (t < 320) smf.ns[t] = 0.f;
    if (t < 208) {
        if (t < 88) *reinterpret_cast<f32x4*>(smf.A + 245 * 128 + t * 16) = (f32x4){0.f,0.f,0.f,0.f};
        else        *reinterpret_cast<f32x4*>(smf.B + 49 * 128 + (t - 88) * 16) = (f32x4){0.f,0.f,0.f,0.f};
    }
    const int nslot5 = (t < 304);
    const float* gp[5];
    int offidx[5];
    #pragma unroll
    for (int i = 0; i < 5; ++i) {
        gp[i] = pbase; offidx[i] = 0;
        if (i < 4 || nslot5) {
            const int s = t + i * 512;
            if (s < 1960) {
                const int kb = s / 245, nw = s - kb * 245;
                const int w = nw / 49, n = nw - w * 49;
                gp[i] = pbase + ((size_t)w * C_CNT + kb * 8) * N_CNT + n;
                offidx[i] = (nw * 128 + ((kb ^ (nw & 7)) << 4)) | (nw << 16);
            } else {
                const int s2 = s - 1960;
                const int kb = s2 / 49, mq = s2 - kb * 49;
                gp[i] = qbase + (size_t)(kb * 8) * N_CNT + mq;
                offidx[i] = (32768 + mq * 128 + ((kb ^ (mq & 7)) << 4)) | ((256 + mq) << 16);
            }
        }
    }
    float v[5][8];
    float ss[5] = {0.f,0.f,0.f,0.f,0.f};
    #pragma unroll
    for (int i = 0; i < 4; ++i)
        #pragma unroll
        for (int j = 0; j < 8; ++j) v[i][j] = gp[i][(size_t)j * N_CNT];
    if (nslot5)
        #pragma unroll
        for (int j = 0; j < 8; ++j) v[4][j] = gp[4][(size_t)j * N_CNT];
    f32x4 acc[2][4];
    #pragma unroll
    for (int i = 0; i < 2; ++i)
        #pragma unroll
        for (int j = 0; j < 4; ++j) acc[i][j] = (f32x4){0.f,0.f,0.f,0.f};
    const int wv = t >> 6, ln = t & 63, lrow = ln & 15, lk = ln >> 4;
    for (int kc = 0; kc < 10; ++kc) {
        #pragma unroll
        for (int i = 0; i < 5; ++i) {
            if (i < 4 || nslot5) {
                bf16x8 pk; float s8 = 0.f;
                #pragma unroll
                for (int j = 0; j < 8; ++j) { const float f = v[i][j]; s8 += f*f; pk[j] = f2bf(f); }
                ss[i] += s8;
                *reinterpret_cast<bf16x8*>(lds + (offidx[i] & 0xFFFF)) = pk;
            }
        }
        __syncthreads();
        if (kc < 9) {
            #pragma unroll
            for (int i = 0; i < 4; ++i) {
                gp[i] += 64 * N_CNT;
                #pragma unroll
                for (int j = 0; j < 8; ++j) v[i][j] = gp[i][(size_t)j * N_CNT];
            }
            if (nslot5) {
                gp[4] += 64 * N_CNT;
                #pragma unroll
                for (int j = 0; j < 8; ++j) v[4][j] = gp[4][(size_t)j * N_CNT];
            }
        }
        #pragma unroll
        for (int ks = 0; ks < 2; ++ks) {
            bf16x8 af[2], bfr[4];
            #pragma unroll
            for (int i = 0; i < 2; ++i) {
                const int row = (wv * 2 + i) * 16 + lrow;
                const int gr = (ks * 4 + lk) ^ (row & 7);
                af[i] = *reinterpret_cast<const bf16x8*>(lds + row * 128 + gr * 16);
            }
            #pragma unroll
            for (int j = 0; j < 4; ++j) {
                const int mq = j * 16 + lrow;
                const int gr = (ks * 4 + lk) ^ (mq & 7);
                bfr[j] = *reinterpret_cast<const bf16x8*>(lds + 32768 + mq * 128 + gr * 16);
            }
            #pragma unroll
            for (int i = 0; i < 2; ++i)
                #pragma unroll
                for (int j = 0; j < 4; ++j)
                    acc[i][j] = __builtin_amdgcn_mfma_f32_16x16x32_bf16(af[i], bfr[j], acc[i][j], 0, 0, 0);
        }
        __syncthreads();
    }
    #pragma unroll
    for (int i = 0; i < 5; ++i)
        if (i < 4 || nslot5) atomicAdd(&smf.ns[offidx[i] >> 16], ss[i]);
    __syncthreads();
    float nq[4];
    #pragma unroll
    for (int j = 0; j < 4; ++j) {
        const int mq = j * 16 + lrow;
        nq[j] = (mq < N_CNT) ? sqrtf(smf.ns[256 + mq]) : 1.f;
    }
    float* obase = out + (size_t)(e * Q_CNT + q) * (W_CNT * N_CNT * N_CNT);
    #pragma unroll
    for (int i = 0; i < 2; ++i) {
        #pragma unroll
        for (int rr = 0; rr < 4; ++rr) {
            const int nw = (wv * 2 + i) * 16 + lk * 4 + rr;
            if (nw < W_CNT * N_CNT) {
                const int w = nw / 49, n = nw - w * 49;
                const float np_ = sqrtf(smf.ns[nw]);
                float* orow = obase + ((size_t)w * N_CNT + n) * N_CNT;
                #pragma unroll
                for (int j = 0; j < 4; ++j) {
                    const int mq = j * 16 + lrow;
                    if (mq < N_CNT) orow[mq] = acc[i][j][rr] / (np_ * nq[j] + 1e-8f);
                }
            }
        }
    }
}

extern "C" void kernel_launch(void* const* d_in, const int* in_sizes, int n_in,
                              void* d_out, int out_size, void* d_ws, size_t ws_size,
                              hipStream_t stream)
{
    const float* proto = (const float*)d_in[0];
    const float* query = (const float*)d_in[1];
    float* out = (float*)d_out;

    if (ws_size < WS_NEEDED) {
        hipLaunchKernelGGL(sim_fallback_kernel, dim3(E_CNT * Q_CNT), dim3(512), 0, stream,
                           proto, query, out);
        return;
    }

    unsigned char* asw = (unsigned char*)d_ws;
    float* pn_part = (float*)((unsigned char*)d_ws + PN_OFF);

    hipLaunchKernelGGL(prep_kernel, dim3(E_CNT * 10), dim3(256), 0, stream,
                       proto, asw, pn_part);
    hipLaunchKernelGGL(gemm_kernel, dim3(E_CNT * Q_CNT), dim3(256), SM_BYTES, stream,
                       query, asw, pn_part, out);
}

// Round 6
// 48.548 us; speedup vs baseline: 2.4914x; 2.4914x over previous
//
#include <hip/hip_runtime.h>
#include <hip/hip_bf16.h>

// SimilarityLayer: out[e,q,w,n,m] = <p[e,w,:,n], q[e,q,:,m]> / (|p||q| + 1e-8)
// E=8 W=5 C=640 N=49 Q=75.
// R6: BARRIER-FREE main loop. prep lays proto into a fragment-ordered bf16
//     A-image (wave fragment = 1KB coalesced dwordx4, no LDS). gemm: one block
//     per (e,q), 4 independent waves, B loaded fp32 + converted in-register,
//     q-norms via shfl_xor, single epilogue barrier for p-norm sharing.
//     Latency hidden by wave-level parallelism instead of intra-gang pipelining.

#define E_CNT 8
#define W_CNT 5
#define C_CNT 640
#define N_CNT 49
#define Q_CNT 75
#define MROWS 245                    // W*N
#define NC32 20                      // K chunks of 32
#define AFRAG_CH (16 * 1024)         // per (e,chunk): 16 row-tiles x 64 lanes x 16B
#define AIMG_E (NC32 * AFRAG_CH)     // 327,680 B per e
#define AIMG_SIZE (E_CNT * AIMG_E)   // 2,621,440
#define PN_OFF AIMG_SIZE
#define PN_PART_BYTES (E_CNT * 10 * MROWS * 4)
#define WS_NEEDED ((size_t)(PN_OFF + PN_PART_BYTES))

typedef __attribute__((ext_vector_type(8))) short bf16x8;
typedef __attribute__((ext_vector_type(4))) float f32x4;

static __device__ __forceinline__ short f2bf(float f) {
    __hip_bfloat16 h = __float2bfloat16(f);
    return *reinterpret_cast<short*>(&h);
}

// ---------------- prep: proto -> fragment-ordered bf16 A image + partial norms
// Element A[nw][k = c64*64 + kb*8 + j] -> chunk c32 = c64*2+(kb>>2),
// row-tile rt = nw>>4, lane ln = (kb&3)*16 + (nw&15), byte (rt*64+ln)*16 + j*2.
__global__ __launch_bounds__(256, 4)
void prep_kernel(const float* __restrict__ proto,
                 unsigned char* __restrict__ aimg,
                 float* __restrict__ pn_part)
{
    __shared__ float pns[MROWS];
    const int b = blockIdx.x;            // 80 = e*10 + c64
    const int e = b / 10, c64 = b % 10;
    const float* pbase = proto + (size_t)e * (W_CNT * C_CNT * N_CNT);
    unsigned char* ebase = aimg + (size_t)e * AIMG_E;
    const int t = threadIdx.x;
    if (t < MROWS) pns[t] = 0.f;
    __syncthreads();

    #pragma unroll
    for (int i = 0; i < 8; ++i) {
        const int s = t + i * 256;       // slot = kb*245 + nw, kb in [0,8)
        int nw, kb;
        bf16x8 pk;
        if (s < 8 * MROWS) {
            kb = s / MROWS;
            nw = s - kb * MROWS;
            const int w = nw / N_CNT, n = nw - w * N_CNT;
            const float* g = pbase + ((size_t)(w * C_CNT + c64 * 64 + kb * 8)) * N_CNT + n;
            float ss = 0.f;
            #pragma unroll
            for (int j = 0; j < 8; ++j) {
                const float f = g[(size_t)j * N_CNT];
                ss += f * f;
                pk[j] = f2bf(f);
            }
            atomicAdd(&pns[nw], ss);
        } else {
            const int x = s - 8 * MROWS; // zero-pad rows 245..255 (x in [0,88))
            nw = MROWS + (x >> 3);
            kb = x & 7;
            pk = (bf16x8){0, 0, 0, 0, 0, 0, 0, 0};
        }
        const int c32 = c64 * 2 + (kb >> 2);
        const int ln2 = ((kb & 3) << 4) | (nw & 15);
        *reinterpret_cast<bf16x8*>(
            ebase + (size_t)c32 * AFRAG_CH + (size_t)((nw >> 4) * 64 + ln2) * 16) = pk;
    }
    __syncthreads();
    if (t < MROWS) pn_part[(size_t)(e * 10 + c64) * MROWS + t] = pns[t];
}

// ---------------- GEMM: one block per (e,q), 4 free-running waves ------------
__global__ __launch_bounds__(256, 2)
void gemm_kernel(const float* __restrict__ query,
                 const unsigned char* __restrict__ aimg,
                 const float* __restrict__ pn_part,
                 float* __restrict__ out)
{
    __shared__ float pnl[256];           // 245 used
    const int b = blockIdx.x;            // 600
    const int e = b & 7;                 // same e -> same XCD -> A image L2-hot
    const int q = b >> 3;
    const int t = threadIdx.x;
    const int wv = t >> 6, ln = t & 63;
    const int lrow = ln & 15, lk = ln >> 4;

    const float* __restrict__ qsl = query + (size_t)(e * Q_CNT + q) * (C_CNT * N_CNT);
    // this wave's A fragments: row-tiles 4wv..4wv+3; per chunk +AFRAG_CH, per fi +1024
    const unsigned char* __restrict__ afrag =
        aimg + (size_t)e * AIMG_E + (size_t)((wv * 4) * 64 + ln) * 16;

    // per-fj column (clamped into range; clamped lanes masked at write)
    int colv[4];
    #pragma unroll
    for (int fj = 0; fj < 4; ++fj) {
        const int c_ = fj * 16 + lrow;
        colv[fj] = (c_ < N_CNT) ? c_ : (N_CNT - 1);
    }
    const int kbase = lk * 8;            // k offset within a 32-chunk

    bf16x8 afA[4], afB[4];
    float vbA[4][8], vbB[4][8];
    float ssq[4] = {0.f, 0.f, 0.f, 0.f};
    f32x4 acc[4][4];
    #pragma unroll
    for (int i = 0; i < 4; ++i)
        #pragma unroll
        for (int j = 0; j < 4; ++j) acc[i][j] = (f32x4){0.f, 0.f, 0.f, 0.f};

#define LOADA(c, dst) do {                                                      \
    const unsigned char* ap_ = afrag + (size_t)(c) * AFRAG_CH;                  \
    _Pragma("unroll")                                                           \
    for (int fi_ = 0; fi_ < 4; ++fi_)                                           \
        dst[fi_] = *reinterpret_cast<const bf16x8*>(ap_ + fi_ * 1024);          \
} while (0)

#define LOADB(c, dst) do {                                                      \
    _Pragma("unroll")                                                           \
    for (int fj_ = 0; fj_ < 4; ++fj_) {                                         \
        _Pragma("unroll")                                                       \
        for (int j_ = 0; j_ < 8; ++j_)                                          \
            dst[fj_][j_] = qsl[((c) * 32 + kbase + j_) * N_CNT + colv[fj_]];    \
    }                                                                           \
} while (0)

#define CONVB(src, bfr) do {                                                    \
    _Pragma("unroll")                                                           \
    for (int fj_ = 0; fj_ < 4; ++fj_) {                                         \
        float s8_ = 0.f;                                                        \
        _Pragma("unroll")                                                       \
        for (int j_ = 0; j_ < 8; ++j_) {                                        \
            const float f_ = src[fj_][j_];                                      \
            s8_ += f_ * f_;                                                     \
            bfr[fj_][j_] = f2bf(f_);                                            \
        }                                                                       \
        ssq[fj_] += s8_;                                                        \
    }                                                                           \
} while (0)

#define DOMFMA(af, bfr) do {                                                    \
    _Pragma("unroll")                                                           \
    for (int fi_ = 0; fi_ < 4; ++fi_)                                           \
        _Pragma("unroll")                                                       \
        for (int fj_ = 0; fj_ < 4; ++fj_)                                       \
            acc[fi_][fj_] = __builtin_amdgcn_mfma_f32_16x16x32_bf16(            \
                af[fi_], bfr[fj_], acc[fi_][fj_], 0, 0, 0);                     \
} while (0)

    // prologue: chunk 0 in flight
    LOADA(0, afA);
    LOADB(0, vbA);

    for (int cc = 0; cc < NC32; cc += 2) {
        // even body: compute chunk cc (bufA), prefetch cc+1 (bufB)
        {
            bf16x8 bfr[4];
            CONVB(vbA, bfr);
            LOADA(cc + 1, afB);          // cc+1 <= 19 always valid
            LOADB(cc + 1, vbB);
            DOMFMA(afA, bfr);
        }
        // odd body: compute chunk cc+1 (bufB), prefetch cc+2 (bufA)
        {
            bf16x8 bfr[4];
            CONVB(vbB, bfr);
            if (cc + 2 < NC32) {
                LOADA(cc + 2, afA);
                LOADB(cc + 2, vbA);
            }
            DOMFMA(afB, bfr);
        }
    }

    // ---- p-norms: sum prep partials, share via LDS (single barrier) ----
    if (t < MROWS) {
        float s = 0.f;
        #pragma unroll
        for (int cc = 0; cc < 10; ++cc)
            s += pn_part[(size_t)(e * 10 + cc) * MROWS + t];
        pnl[t] = sqrtf(s);
    }
    __syncthreads();

    // ---- q-norms: reduce ssq across the 4 lk groups (lanes ln^16, ln^32) ----
    float nq4[4];
    #pragma unroll
    for (int fj = 0; fj < 4; ++fj) {
        float s = ssq[fj];
        s += __shfl_xor(s, 16);
        s += __shfl_xor(s, 32);
        nq4[fj] = sqrtf(s);
    }

    // ---- epilogue: contiguous slice out[(e*75+q)*12005 + nw*49 + m] ----
    float* __restrict__ osl = out + (size_t)(e * Q_CNT + q) * (W_CNT * N_CNT * N_CNT);
    #pragma unroll
    for (int fi = 0; fi < 4; ++fi) {
        #pragma unroll
        for (int rr = 0; rr < 4; ++rr) {
            const int nw = wv * 64 + fi * 16 + lk * 4 + rr;   // D row = (lane>>4)*4+reg
            if (nw < MROWS) {
                const float np_ = pnl[nw];
                #pragma unroll
                for (int fj = 0; fj < 4; ++fj) {
                    const int m = fj * 16 + lrow;             // D col = lane&15
                    if (m < N_CNT) {
                        const float den = np_ * nq4[fj] + 1e-8f;
                        osl[nw * N_CNT + m] = acc[fi][fj][rr] * __builtin_amdgcn_rcpf(den);
                    }
                }
            }
        }
    }
#undef LOADA
#undef LOADB
#undef CONVB
#undef DOMFMA
}

// ---------------- fallback (R2 kernel) if ws too small -----------------------
struct SMemFB {
    unsigned char A[256 * 128];
    unsigned char B[64 * 128];
    float ns[320];
};

__global__ __launch_bounds__(512, 4)
void sim_fallback_kernel(const float* __restrict__ proto,
                         const float* __restrict__ query,
                         float* __restrict__ out)
{
    __shared__ SMemFB smf;
    const int t = threadIdx.x;
    const int e = blockIdx.x / Q_CNT;
    const int q = blockIdx.x - e * Q_CNT;
    const float* pbase = proto + (size_t)e * (W_CNT * C_CNT * N_CNT);
    const float* qbase = query + ((size_t)e * Q_CNT + q) * (C_CNT * N_CNT);
    unsigned char* lds = (unsigned char*)&smf;
    if (t < 320) smf.ns[t] = 0.f;
    if (t < 208) {
        if (t < 88) *reinterpret_cast<f32x4*>(smf.A + 245 * 128 + t * 16) = (f32x4){0.f,0.f,0.f,0.f};
        else        *reinterpret_cast<f32x4*>(smf.B + 49 * 128 + (t - 88) * 16) = (f32x4){0.f,0.f,0.f,0.f};
    }
    const int nslot5 = (t < 304);
    const float* gp[5];
    int offidx[5];
    #pragma unroll
    for (int i = 0; i < 5; ++i) {
        gp[i] = pbase; offidx[i] = 0;
        if (i < 4 || nslot5) {
            const int s = t + i * 512;
            if (s < 1960) {
                const int kb = s / 245, nw = s - kb * 245;
                const int w = nw / 49, n = nw - w * 49;
                gp[i] = pbase + ((size_t)w * C_CNT + kb * 8) * N_CNT + n;
                offidx[i] = (nw * 128 + ((kb ^ (nw & 7)) << 4)) | (nw << 16);
            } else {
                const int s2 = s - 1960;
                const int kb = s2 / 49, mq = s2 - kb * 49;
                gp[i] = qbase + (size_t)(kb * 8) * N_CNT + mq;
                offidx[i] = (32768 + mq * 128 + ((kb ^ (mq & 7)) << 4)) | ((256 + mq) << 16);
            }
        }
    }
    float v[5][8];
    float ss[5] = {0.f,0.f,0.f,0.f,0.f};
    #pragma unroll
    for (int i = 0; i < 4; ++i)
        #pragma unroll
        for (int j = 0; j < 8; ++j) v[i][j] = gp[i][(size_t)j * N_CNT];
    if (nslot5)
        #pragma unroll
        for (int j = 0; j < 8; ++j) v[4][j] = gp[4][(size_t)j * N_CNT];
    f32x4 acc[2][4];
    #pragma unroll
    for (int i = 0; i < 2; ++i)
        #pragma unroll
        for (int j = 0; j < 4; ++j) acc[i][j] = (f32x4){0.f,0.f,0.f,0.f};
    const int wv = t >> 6, ln = t & 63, lrow = ln & 15, lk = ln >> 4;
    for (int kc = 0; kc < 10; ++kc) {
        #pragma unroll
        for (int i = 0; i < 5; ++i) {
            if (i < 4 || nslot5) {
                bf16x8 pk; float s8 = 0.f;
                #pragma unroll
                for (int j = 0; j < 8; ++j) { const float f = v[i][j]; s8 += f*f; pk[j] = f2bf(f); }
                ss[i] += s8;
                *reinterpret_cast<bf16x8*>(lds + (offidx[i] & 0xFFFF)) = pk;
            }
        }
        __syncthreads();
        if (kc < 9) {
            #pragma unroll
            for (int i = 0; i < 4; ++i) {
                gp[i] += 64 * N_CNT;
                #pragma unroll
                for (int j = 0; j < 8; ++j) v[i][j] = gp[i][(size_t)j * N_CNT];
            }
            if (nslot5) {
                gp[4] += 64 * N_CNT;
                #pragma unroll
                for (int j = 0; j < 8; ++j) v[4][j] = gp[4][(size_t)j * N_CNT];
            }
        }
        #pragma unroll
        for (int ks = 0; ks < 2; ++ks) {
            bf16x8 af[2], bfr[4];
            #pragma unroll
            for (int i = 0; i < 2; ++i) {
                const int row = (wv * 2 + i) * 16 + lrow;
                const int gr = (ks * 4 + lk) ^ (row & 7);
                af[i] = *reinterpret_cast<const bf16x8*>(lds + row * 128 + gr * 16);
            }
            #pragma unroll
            for (int j = 0; j < 4; ++j) {
                const int mq = j * 16 + lrow;
                const int gr = (ks * 4 + lk) ^ (mq & 7);
                bfr[j] = *reinterpret_cast<const bf16x8*>(lds + 32768 + mq * 128 + gr * 16);
            }
            #pragma unroll
            for (int i = 0; i < 2; ++i)
                #pragma unroll
                for (int j = 0; j < 4; ++j)
                    acc[i][j] = __builtin_amdgcn_mfma_f32_16x16x32_bf16(af[i], bfr[j], acc[i][j], 0, 0, 0);
        }
        __syncthreads();
    }
    #pragma unroll
    for (int i = 0; i < 5; ++i)
        if (i < 4 || nslot5) atomicAdd(&smf.ns[offidx[i] >> 16], ss[i]);
    __syncthreads();
    float nq[4];
    #pragma unroll
    for (int j = 0; j < 4; ++j) {
        const int mq = j * 16 + lrow;
        nq[j] = (mq < N_CNT) ? sqrtf(smf.ns[256 + mq]) : 1.f;
    }
    float* obase = out + (size_t)(e * Q_CNT + q) * (W_CNT * N_CNT * N_CNT);
    #pragma unroll
    for (int i = 0; i < 2; ++i) {
        #pragma unroll
        for (int rr = 0; rr < 4; ++rr) {
            const int nw = (wv * 2 + i) * 16 + lk * 4 + rr;
            if (nw < W_CNT * N_CNT) {
                const int w = nw / 49, n = nw - w * 49;
                const float np_ = sqrtf(smf.ns[nw]);
                float* orow = obase + ((size_t)w * N_CNT + n) * N_CNT;
                #pragma unroll
                for (int j = 0; j < 4; ++j) {
                    const int mq = j * 16 + lrow;
                    if (mq < N_CNT) orow[mq] = acc[i][j][rr] / (np_ * nq[j] + 1e-8f);
                }
            }
        }
    }
}

extern "C" void kernel_launch(void* const* d_in, const int* in_sizes, int n_in,
                              void* d_out, int out_size, void* d_ws, size_t ws_size,
                              hipStream_t stream)
{
    const float* proto = (const float*)d_in[0];
    const float* query = (const float*)d_in[1];
    float* out = (float*)d_out;

    if (ws_size < WS_NEEDED) {
        hipLaunchKernelGGL(sim_fallback_kernel, dim3(E_CNT * Q_CNT), dim3(512), 0, stream,
                           proto, query, out);
        return;
    }

    unsigned char* aimg = (unsigned char*)d_ws;
    float* pn_part = (float*)((unsigned char*)d_ws + PN_OFF);

    hipLaunchKernelGGL(prep_kernel, dim3(E_CNT * 10), dim3(256), 0, stream,
                       proto, aimg, pn_part);
    hipLaunchKernelGGL(gemm_kernel, dim3(E_CNT * Q_CNT), dim3(256), 0, stream,
                       query, aimg, pn_part, out);
}